// Round 3
// baseline (1264.933 us; speedup 1.0000x reference)
//
#include <hip/hip_runtime.h>
#include <math.h>

#define NB 64
#define NT 512
#define NVAR 16
#define VDIM 16
#define DD 64
#define FF 256
#define BT (NB*NT)
#define LN_EPS 1e-3f

// cproj[b][n][d] = sum_k ctx[b][k] * Wctx[n][k][d]   (broadcast over T, hoisted)
__global__ void cproj_kernel(const float* __restrict__ ctx,
                             const float* __restrict__ Wctx,
                             float* __restrict__ cproj) {
    int bn = blockIdx.x;
    int b = bn >> 4, n = bn & 15;
    int d = threadIdx.x;
    const float* __restrict__ w = Wctx + n * DD * DD;
    const float* __restrict__ c = ctx + b * DD;
    float acc = 0.f;
    #pragma unroll 8
    for (int k = 0; k < DD; ++k)
        acc += c[k] * w[k * DD + d];
    cproj[bn * DD + d] = acc;
}

// 32-wide fma of one weight half-row (8 float4s) into acc
#define FMA32Q(acc_, x_, w_) { \
    _Pragma("unroll") \
    for (int q = 0; q < 8; ++q) { \
        acc_[4*q+0] += x_ * w_[q].x; \
        acc_[4*q+1] += x_ * w_[q].y; \
        acc_[4*q+2] += x_ * w_[q].z; \
        acc_[4*q+3] += x_ * w_[q].w; \
    } }

// GEMV over K rows, 32 output dims. W points at the half-row start (already
// includes +vz so loads go through VMEM, not SMEM: vmcnt is in-order ->
// partial waits -> pipelined). Double-buffered weight rows (2x8 float4).
// x streamed from the wave-private LDS buffer (lgkm carries ONLY in-order ds).
__device__ __forceinline__ void gemv32(float* __restrict__ acc,
                                       const float* __restrict__ W, int K,
                                       const float* __restrict__ xbuf,
                                       int rowb, int swl) {
    float4 wa[8], wb[8];
    #pragma unroll
    for (int q = 0; q < 8; ++q) wa[q] = *(const float4*)(W + 4*q);
    #pragma clang loop unroll(disable)
    for (int k = 0; k < K; k += 2) {
        #pragma unroll
        for (int q = 0; q < 8; ++q) wb[q] = *(const float4*)(W + (k+1)*DD + 4*q);
        float x0 = xbuf[rowb + (k ^ swl)];
        FMA32Q(acc, x0, wa);
        int kn = (k + 2 < K) ? (k + 2) : 0;
        #pragma unroll
        for (int q = 0; q < 8; ++q) wa[q] = *(const float4*)(W + kn*DD + 4*q);
        float x1 = xbuf[rowb + ((k+1) ^ swl)];
        FMA32Q(acc, x1, wb);
    }
}

__global__ __launch_bounds__(256, 2)
void vsn_kernel(const float* __restrict__ inp,
                const float* __restrict__ Wt, const float* __restrict__ bt,
                const float* __restrict__ W1, const float* __restrict__ b1,
                const float* __restrict__ W2, const float* __restrict__ b2,
                const float* __restrict__ Wg, const float* __restrict__ bg,
                const float* __restrict__ Wp, const float* __restrict__ bp,
                const float* __restrict__ gamma_, const float* __restrict__ beta_,
                const float* __restrict__ Ws, const float* __restrict__ bs,
                const float* __restrict__ cproj,
                float* __restrict__ out_sel, float* __restrict__ out_w) {

    __shared__ float s_buf[4][DD * DD];   // 64KB per-wave scratch (row=token, xor-swizzled cols)
    __shared__ float s_sel[DD * DD];      // 16KB selection accumulator [d][tok ^ (d&31)]

    const int tid   = threadIdx.x;
    const int lane  = tid & 63;
    const int wv    = __builtin_amdgcn_readfirstlane(tid >> 6);
    const int tile0 = blockIdx.x * 64;
    const int b     = blockIdx.x >> 3;     // tile0 / NT

    // Opaque zero in a VGPR: added to weight pointers so divergence analysis
    // cannot scalarize them into s_load (SMEM is out-of-order on lgkmcnt ->
    // every use forces lgkmcnt(0) full drain -> no pipelining).
    int vz;
    asm volatile("v_mov_b32 %0, 0" : "=v"(vz));

    float* buf = &s_buf[wv][0];
    const int swl = lane & 31;
    const int rowb = lane * 64;

    for (int i = tid; i < DD * DD; i += 256) s_sel[i] = 0.f;
    __syncthreads();

    // ---------------- logits + softmax (each wave computes full softmax) ----
    float lg[16];
    #pragma unroll
    for (int n = 0; n < 16; ++n) lg[n] = bs[n];

    for (int c = 0; c < 16; ++c) {
        // stage 64 tokens x 16 floats (feature cols c*16..c*16+15)
        #pragma unroll
        for (int j = 0; j < 4; ++j) {
            int idx = j * 64 + lane;
            int tok = idx >> 2, f4 = (idx & 3) * 4;
            float4 v = *(const float4*)(inp + (tile0 + tok) * FF + c * VDIM + f4);
            int sw = tok & 31;
            buf[tok * 64 + ((f4 + 0) ^ sw)] = v.x;
            buf[tok * 64 + ((f4 + 1) ^ sw)] = v.y;
            buf[tok * 64 + ((f4 + 2) ^ sw)] = v.z;
            buf[tok * 64 + ((f4 + 3) ^ sw)] = v.w;
        }
        const float* Wsc = Ws + c * 16 * 16 + vz;   // VMEM-forced
        float4 wsa[4], wsb[4];
        #pragma unroll
        for (int q = 0; q < 4; ++q) wsa[q] = *(const float4*)(Wsc + 4*q);
        #pragma clang loop unroll(disable)
        for (int k = 0; k < 16; k += 2) {
            #pragma unroll
            for (int q = 0; q < 4; ++q) wsb[q] = *(const float4*)(Wsc + (k+1)*16 + 4*q);
            float x0 = buf[rowb + (k ^ swl)];
            #pragma unroll
            for (int q = 0; q < 4; ++q) {
                lg[4*q+0] += x0 * wsa[q].x; lg[4*q+1] += x0 * wsa[q].y;
                lg[4*q+2] += x0 * wsa[q].z; lg[4*q+3] += x0 * wsa[q].w;
            }
            int kn = (k + 2 < 16) ? (k + 2) : 0;
            #pragma unroll
            for (int q = 0; q < 4; ++q) wsa[q] = *(const float4*)(Wsc + kn*16 + 4*q);
            float x1 = buf[rowb + ((k+1) ^ swl)];
            #pragma unroll
            for (int q = 0; q < 4; ++q) {
                lg[4*q+0] += x1 * wsb[q].x; lg[4*q+1] += x1 * wsb[q].y;
                lg[4*q+2] += x1 * wsb[q].z; lg[4*q+3] += x1 * wsb[q].w;
            }
        }
    }
    float mx = lg[0];
    #pragma unroll
    for (int n = 1; n < 16; ++n) mx = fmaxf(mx, lg[n]);
    float w[16];
    float sum = 0.f;
    #pragma unroll
    for (int n = 0; n < 16; ++n) { w[n] = __expf(lg[n] - mx); sum += w[n]; }
    float rsum = 1.f / sum;
    #pragma unroll
    for (int n = 0; n < 16; ++n) w[n] *= rsum;

    if (wv == 0) {
        #pragma unroll
        for (int n = 0; n < 16; ++n)
            out_w[(tile0 + lane) * 16 + n] = w[n];
    }

    // Extract this wave's 4 selection weights with CONSTANT register indices.
    float wsel0, wsel1, wsel2, wsel3;
    if (wv == 0)      { wsel0 = w[0];  wsel1 = w[1];  wsel2 = w[2];  wsel3 = w[3];  }
    else if (wv == 1) { wsel0 = w[4];  wsel1 = w[5];  wsel2 = w[6];  wsel3 = w[7];  }
    else if (wv == 2) { wsel0 = w[8];  wsel1 = w[9];  wsel2 = w[10]; wsel3 = w[11]; }
    else              { wsel0 = w[12]; wsel1 = w[13]; wsel2 = w[14]; wsel3 = w[15]; }

    // ---------------- per-variable GRN chain (4 vars per wave) --------------
    #pragma clang loop unroll(disable)
    for (int vi = 0; vi < 4; ++vi) {
        const int n = wv * 4 + vi;
        const float wn = (vi == 0) ? wsel0 : (vi == 1) ? wsel1 : (vi == 2) ? wsel2 : wsel3;
        const float* pwt = Wt + n * VDIM * DD + vz;   // all VMEM-forced
        const float* pw1 = W1 + n * DD * DD + vz;
        const float* pw2 = W2 + n * DD * DD + vz;
        const float* pwg = Wg + n * DD * DD + vz;
        const float* pwp = Wp + n * DD * DD + vz;
        const float* __restrict__ pcp = cproj + (b * NVAR + n) * DD;

        // stage xv[:, n*16 .. n*16+15] into buf cols (k ^ (tok&31)), k<16
        #pragma unroll
        for (int j = 0; j < 4; ++j) {
            int idx = j * 64 + lane;
            int tok = idx >> 2, f4 = (idx & 3) * 4;
            float4 v = *(const float4*)(inp + (tile0 + tok) * FF + n * VDIM + f4);
            int sw = tok & 31;
            buf[tok * 64 + ((f4 + 0) ^ sw)] = v.x;
            buf[tok * 64 + ((f4 + 1) ^ sw)] = v.y;
            buf[tok * 64 + ((f4 + 2) ^ sw)] = v.z;
            buf[tok * 64 + ((f4 + 3) ^ sw)] = v.w;
        }

        // ---- t = xv @ Wt + bt : both halves in regs, then -> buf ----
        {
            float ta[32], tb[32];
            #pragma unroll
            for (int j = 0; j < 32; ++j) ta[j] = bt[n * DD + j];
            #pragma unroll
            for (int j = 0; j < 32; ++j) tb[j] = bt[n * DD + 32 + j];
            gemv32(ta, pwt, VDIM, buf, rowb, swl);
            gemv32(tb, pwt + 32, VDIM, buf, rowb, swl);
            #pragma unroll
            for (int j = 0; j < 32; ++j) {
                buf[rowb + (j ^ swl)] = ta[j];
                buf[rowb + ((j + 32) ^ swl)] = tb[j];
            }
        }

        // ---- res = t @ Wp + bp : kept in regs to the end ----
        float ra[32], rb[32];
        #pragma unroll
        for (int j = 0; j < 32; ++j) ra[j] = bp[n * DD + j];
        #pragma unroll
        for (int j = 0; j < 32; ++j) rb[j] = bp[n * DD + 32 + j];
        gemv32(ra, pwp, DD, buf, rowb, swl);
        gemv32(rb, pwp + 32, DD, buf, rowb, swl);

        // ---- buf = t + cproj (in place) ----
        #pragma unroll 8
        for (int d = 0; d < 64; ++d)
            buf[rowb + (d ^ swl)] += pcp[d];

        // ---- h1 = elu((t+cproj) @ W1 + b1) : regs, then -> buf ----
        {
            float ha[32], hb[32];
            #pragma unroll
            for (int j = 0; j < 32; ++j) ha[j] = b1[n * DD + j];
            #pragma unroll
            for (int j = 0; j < 32; ++j) hb[j] = b1[n * DD + 32 + j];
            gemv32(ha, pw1, DD, buf, rowb, swl);
            gemv32(hb, pw1 + 32, DD, buf, rowb, swl);
            #pragma unroll
            for (int j = 0; j < 32; ++j) {
                ha[j] = ha[j] > 0.f ? ha[j] : (__expf(ha[j]) - 1.f);
                hb[j] = hb[j] > 0.f ? hb[j] : (__expf(hb[j]) - 1.f);
            }
            #pragma unroll
            for (int j = 0; j < 32; ++j) {
                buf[rowb + (j ^ swl)] = ha[j];
                buf[rowb + ((j + 32) ^ swl)] = hb[j];
            }
        }

        // ---- h2 = h1 @ W2 + b2 : regs, then -> buf ----
        {
            float ha[32], hb[32];
            #pragma unroll
            for (int j = 0; j < 32; ++j) ha[j] = b2[n * DD + j];
            #pragma unroll
            for (int j = 0; j < 32; ++j) hb[j] = b2[n * DD + 32 + j];
            gemv32(ha, pw2, DD, buf, rowb, swl);
            gemv32(hb, pw2 + 32, DD, buf, rowb, swl);
            #pragma unroll
            for (int j = 0; j < 32; ++j) {
                buf[rowb + (j ^ swl)] = ha[j];
                buf[rowb + ((j + 32) ^ swl)] = hb[j];
            }
        }

        // ---- gate halves + z; h2 read back from buf ----
        float z[64];
        {
            float ga[32];
            #pragma unroll
            for (int j = 0; j < 32; ++j) ga[j] = bg[n * DD + j];
            gemv32(ga, pwg, DD, buf, rowb, swl);
            #pragma unroll
            for (int j = 0; j < 32; ++j) {
                float h2d = buf[rowb + (j ^ swl)];
                float gd = 1.f / (1.f + __expf(-ga[j]));
                z[j] = gd * h2d + ra[j];
            }
        }
        {
            float gb[32];
            #pragma unroll
            for (int j = 0; j < 32; ++j) gb[j] = bg[n * DD + 32 + j];
            gemv32(gb, pwg + 32, DD, buf, rowb, swl);
            #pragma unroll
            for (int j = 0; j < 32; ++j) {
                float h2d = buf[rowb + ((j + 32) ^ swl)];
                float gd = 1.f / (1.f + __expf(-gb[j]));
                z[j + 32] = gd * h2d + rb[j];
            }
        }

        // ---- LayerNorm over the 64 in-lane values + weighted selection ----
        float mu = 0.f;
        #pragma unroll
        for (int d = 0; d < 64; ++d) mu += z[d];
        mu *= (1.f / 64.f);
        float var = 0.f;
        #pragma unroll
        for (int d = 0; d < 64; ++d) { z[d] -= mu; var += z[d] * z[d]; }
        float rstd = rsqrtf(var * (1.f / 64.f) + LN_EPS);
        #pragma unroll
        for (int d = 0; d < 64; ++d) {
            float y = z[d] * rstd * gamma_[n * DD + d] + beta_[n * DD + d];
            atomicAdd(&s_sel[d * 64 + (lane ^ (d & 31))], wn * y);
        }
    }

    __syncthreads();

    #pragma unroll
    for (int i = 0; i < 16; ++i) {
        int tok = i * 4 + (tid >> 6);
        int d = tid & 63;
        out_sel[(tile0 + tok) * DD + d] = s_sel[d * 64 + (tok ^ (d & 31))];
    }
}

extern "C" void kernel_launch(void* const* d_in, const int* in_sizes, int n_in,
                              void* d_out, int out_size, void* d_ws, size_t ws_size,
                              hipStream_t stream) {
    const float* inp  = (const float*)d_in[0];
    const float* ctx  = (const float*)d_in[1];
    const float* Wt   = (const float*)d_in[2];
    const float* bt   = (const float*)d_in[3];
    const float* Wctx = (const float*)d_in[4];
    const float* W1   = (const float*)d_in[5];
    const float* b1   = (const float*)d_in[6];
    const float* W2   = (const float*)d_in[7];
    const float* b2   = (const float*)d_in[8];
    const float* Wg   = (const float*)d_in[9];
    const float* bg   = (const float*)d_in[10];
    const float* Wp   = (const float*)d_in[11];
    const float* bp   = (const float*)d_in[12];
    const float* gm   = (const float*)d_in[13];
    const float* bt2  = (const float*)d_in[14];
    const float* Ws   = (const float*)d_in[15];
    const float* bs   = (const float*)d_in[16];

    float* out_sel = (float*)d_out;
    float* out_w   = out_sel + (size_t)BT * DD;
    float* cproj   = (float*)d_ws;   // 64*16*64 floats = 256KB

    cproj_kernel<<<NB * NVAR, DD, 0, stream>>>(ctx, Wctx, cproj);
    vsn_kernel<<<BT / 64, 256, 0, stream>>>(inp, Wt, bt, W1, b1, W2, b2,
                                            Wg, bg, Wp, bp, gm, bt2, Ws, bs,
                                            cproj, out_sel, out_w);
}

// Round 4
// 351.807 us; speedup vs baseline: 3.5955x; 3.5955x over previous
//
#include <hip/hip_runtime.h>
#include <math.h>

#define NB 64
#define NT 512
#define NVAR 16
#define VDIM 16
#define DD 64
#define FF 256
#define BT (NB*NT)
#define LN_EPS 1e-3f

typedef __attribute__((ext_vector_type(8))) short bf8;   // 8 bf16 = one MFMA A/B operand
typedef __attribute__((ext_vector_type(4))) float f4;
typedef __attribute__((ext_vector_type(4))) int i4;
typedef __attribute__((ext_vector_type(4))) unsigned u4;
typedef __attribute__((ext_vector_type(2))) float f2;

// ---- ws layout (bytes) ----
#define CPROJ_OFF   0
#define WTP_OFF     262144              // 16 vars x 4 frags x 64 lanes x 16B = 64KB
#define BIGP_OFF    (262144+65536)      // 16 vars x 4 mats x 16 frags x 64 x 16B = 1MB
#define WSP_OFF     (262144+65536+1048576) // 16 frags x 64 x 16B = 16KB
// mats: 0=Wp 1=W1 2=W2 3=Wg

// RNE fp32 -> bf16 split helpers. hi = RNE(x); lo = x - hi (then RNE'd when packed).
__device__ __forceinline__ void split1(float x, unsigned &hb, float &lo) {
    unsigned u = __builtin_bit_cast(unsigned, x);
    unsigned r = u + 0x7fffu + ((u >> 16) & 1u);
    hb = r >> 16;
    lo = x - __builtin_bit_cast(float, r & 0xffff0000u);
}
__device__ __forceinline__ unsigned rnepk(float x, float y) {
    unsigned a = __builtin_bit_cast(unsigned, x);
    unsigned b = __builtin_bit_cast(unsigned, y);
    a = a + 0x7fffu + ((a >> 16) & 1u);
    b = b + 0x7fffu + ((b >> 16) & 1u);
    return (a >> 16) | (b & 0xffff0000u);
}
__device__ __forceinline__ void split4(f4 v, unsigned &h0, unsigned &h1,
                                       unsigned &l0, unsigned &l1) {
    unsigned b0,b1,b2,b3; float q0,q1,q2,q3;
    split1(v.x,b0,q0); split1(v.y,b1,q1); split1(v.z,b2,q2); split1(v.w,b3,q3);
    h0 = b0 | (b1<<16); h1 = b2 | (b3<<16);
    l0 = rnepk(q0,q1); l1 = rnepk(q2,q3);
}
__device__ __forceinline__ bf8 mkfrag(unsigned w0, unsigned w1) {
    i4 t; t.x = (int)w0; t.y = (int)w1; t.z = 0; t.w = 0;  // slots 4..7 zero
    return __builtin_bit_cast(bf8, t);
}
__device__ __forceinline__ float bflo(unsigned w){ return __builtin_bit_cast(float, w<<16); }
__device__ __forceinline__ float bfhi(unsigned w){ return __builtin_bit_cast(float, w & 0xffff0000u); }

__device__ __forceinline__ f4 mfma3(f4 acc, bf8 Ah, bf8 Al, bf8 Bh, bf8 Bl) {
    acc = __builtin_amdgcn_mfma_f32_16x16x32_bf16(Ah, Bh, acc, 0,0,0);
    acc = __builtin_amdgcn_mfma_f32_16x16x32_bf16(Ah, Bl, acc, 0,0,0);
    acc = __builtin_amdgcn_mfma_f32_16x16x32_bf16(Al, Bh, acc, 0,0,0);
    return acc;
}

__device__ __forceinline__ void init_bias(const float* p, int qd, f4 acc[4][2]) {
    #pragma unroll
    for (int Mi = 0; Mi < 4; ++Mi) {
        f4 b = *(const f4*)(p + 16*Mi + 4*qd);
        acc[Mi][0] = b; acc[Mi][1] = b;
    }
}
__device__ __forceinline__ void acc_to_frags(const f4 acc[4][2],
        unsigned fh[4][2][2], unsigned fl[4][2][2]) {
    #pragma unroll
    for (int Ks = 0; Ks < 4; ++Ks)
        #pragma unroll
        for (int Nj = 0; Nj < 2; ++Nj)
            split4(acc[Ks][Nj], fh[Ks][Nj][0], fh[Ks][Nj][1],
                                fl[Ks][Nj][0], fl[Ks][Nj][1]);
}
// One 64x64(xK=64) GEMM-stage: acc[Mi][Nj] += Wpack^T . Bfrags   (3-product split)
__device__ __forceinline__ void run_stage(const u4* __restrict__ ap, int lane,
        const unsigned fh[4][2][2], const unsigned fl[4][2][2], f4 acc[4][2]) {
    u4 wcur[4], wnxt[4];
    #pragma unroll
    for (int Mi = 0; Mi < 4; ++Mi) wcur[Mi] = ap[Mi*64 + lane];
    #pragma unroll
    for (int Ks = 0; Ks < 4; ++Ks) {
        if (Ks < 3) {
            #pragma unroll
            for (int Mi = 0; Mi < 4; ++Mi) wnxt[Mi] = ap[((Ks+1)*4+Mi)*64 + lane];
        }
        #pragma unroll
        for (int Mi = 0; Mi < 4; ++Mi) {
            bf8 Ah = mkfrag(wcur[Mi].x, wcur[Mi].y);
            bf8 Al = mkfrag(wcur[Mi].z, wcur[Mi].w);
            #pragma unroll
            for (int Nj = 0; Nj < 2; ++Nj) {
                bf8 Bh = mkfrag(fh[Ks][Nj][0], fh[Ks][Nj][1]);
                bf8 Bl = mkfrag(fl[Ks][Nj][0], fl[Ks][Nj][1]);
                acc[Mi][Nj] = mfma3(acc[Mi][Nj], Ah, Al, Bh, Bl);
            }
        }
        #pragma unroll
        for (int Mi = 0; Mi < 4; ++Mi) wcur[Mi] = wnxt[Mi];
    }
}

// cproj[b][n][d] = sum_k ctx[b][k] * Wctx[n][k][d]
__global__ void cproj_kernel(const float* __restrict__ ctx,
                             const float* __restrict__ Wctx,
                             float* __restrict__ cproj) {
    int bn = blockIdx.x;
    int b = bn >> 4, n = bn & 15;
    int d = threadIdx.x;
    const float* __restrict__ w = Wctx + n * DD * DD;
    const float* __restrict__ c = ctx + b * DD;
    float acc = 0.f;
    #pragma unroll 8
    for (int k = 0; k < DD; ++k) acc += c[k] * w[k * DD + d];
    cproj[bn * DD + d] = acc;
}

// Pre-pack all weights into MFMA A-fragment order, bf16 hi/lo, 16B per (frag,lane):
// A^T frag (Mi,Ks): lane L holds W[k = 16*Ks + 4*(L>>4) + j][m = 16*Mi + (L&15)], j=0..3.
__global__ void pack_kernel(const float* __restrict__ Wt, const float* __restrict__ W1,
                            const float* __restrict__ W2, const float* __restrict__ Wg,
                            const float* __restrict__ Wp, const float* __restrict__ Ws,
                            u4* __restrict__ wtp, u4* __restrict__ bigp,
                            u4* __restrict__ wsp) {
    int t = blockIdx.x * 256 + threadIdx.x;
    float v0, v1, v2, v3; u4* dst;
    if (t < 65536) {
        int lane = t & 63, Mi = (t>>6)&3, Ks = (t>>8)&3, mat = (t>>10)&3, var = t>>12;
        const float* W = (mat==0) ? Wp : (mat==1) ? W1 : (mat==2) ? W2 : Wg;
        const float* src = W + var*4096;
        int m = 16*Mi + (lane&15), k0 = 16*Ks + 4*(lane>>4);
        v0 = src[(k0+0)*64+m]; v1 = src[(k0+1)*64+m];
        v2 = src[(k0+2)*64+m]; v3 = src[(k0+3)*64+m];
        dst = bigp + ((var*4+mat)*16 + Ks*4 + Mi)*64 + lane;
    } else if (t < 65536+4096) {
        int r = t - 65536;
        int lane = r & 63, Mi = (r>>6)&3, var = r>>8;
        int m = 16*Mi + (lane&15), k0 = 4*(lane>>4);
        const float* src = Wt + var*1024;
        v0 = src[(k0+0)*64+m]; v1 = src[(k0+1)*64+m];
        v2 = src[(k0+2)*64+m]; v3 = src[(k0+3)*64+m];
        dst = wtp + (var*4+Mi)*64 + lane;
    } else if (t < 65536+4096+1024) {
        int r = t - 69632;
        int lane = r & 63, Ks = r >> 6;
        int m = lane & 15, k0 = 16*Ks + 4*(lane>>4);
        v0 = Ws[(k0+0)*16+m]; v1 = Ws[(k0+1)*16+m];
        v2 = Ws[(k0+2)*16+m]; v3 = Ws[(k0+3)*16+m];
        dst = wsp + Ks*64 + lane;
    } else return;
    f4 v; v.x=v0; v.y=v1; v.z=v2; v.w=v3;
    unsigned h0,h1,l0,l1; split4(v,h0,h1,l0,l1);
    u4 o; o.x=h0; o.y=h1; o.z=l0; o.w=l1;
    *dst = o;
}

// Main: block = 512 threads = 8 waves, 64 tokens.
// wave wv: half = wv&1 (32 tokens), var-group g = wv>>1 (vars 4g..4g+3).
// All activations live transposed (d on M, tok on N): C-regs of one stage ARE the
// B-operand of the next (in-lane bf16 split; logical k mapped 4-per-quad into
// slots 0..3 of mfma_f32_16x16x32_bf16, slots 4..7 zero in A).
#define RES_OFF  0        // 8 waves x 64 lanes x 34 dw = 17408
#define SEL_OFF  17408    // 2 halves x 64 d x 33 = 4224
#define WSEL_OFF 21632    // 2 halves x 16 vars x 33 = 1056
#define SMEM_DW  22688

__global__ __launch_bounds__(512, 2)
void vsn_kernel(const float* __restrict__ inp,
                const u4* __restrict__ wtp, const u4* __restrict__ bigp,
                const u4* __restrict__ wsp,
                const float* __restrict__ bt, const float* __restrict__ b1,
                const float* __restrict__ b2, const float* __restrict__ bg,
                const float* __restrict__ bp,
                const float* __restrict__ gamma_, const float* __restrict__ beta_,
                const float* __restrict__ bs,
                const float* __restrict__ cproj,
                float* __restrict__ out_sel, float* __restrict__ out_w) {
    __shared__ float smem[SMEM_DW];

    const int tid  = threadIdx.x;
    const int lane = tid & 63;
    const int wv   = tid >> 6;
    const int half = wv & 1;
    const int g    = wv >> 1;
    const int qd   = lane >> 4;
    const int l15  = lane & 15;
    const int tile0 = blockIdx.x * 64;
    const int b     = blockIdx.x >> 3;
    const int resbase = RES_OFF + wv * 2176;
    const int selbase = SEL_OFF + half * 2112;

    for (int i = tid; i < 4224; i += 512) smem[SEL_OFF + i] = 0.f;

    const float* row0 = inp + (size_t)(tile0 + half*32 + l15) * FF;   // Nj=0 token row
    const float* row1 = row0 + 16 * FF;                               // Nj=1

    // ---------------- logits via MFMA + softmax ----------------
    {
        f4 lacc[2];
        f4 bsv = *(const f4*)(bs + 4*qd);
        lacc[0] = bsv; lacc[1] = bsv;
        #pragma unroll
        for (int Ks = 0; Ks < 16; ++Ks) {
            u4 w = wsp[Ks*64 + lane];
            bf8 Ah = mkfrag(w.x, w.y), Al = mkfrag(w.z, w.w);
            f4 v0 = *(const f4*)(row0 + 16*Ks + 4*qd);
            f4 v1 = *(const f4*)(row1 + 16*Ks + 4*qd);
            unsigned h0,h1,l0,l1;
            split4(v0,h0,h1,l0,l1);
            lacc[0] = mfma3(lacc[0], Ah, Al, mkfrag(h0,h1), mkfrag(l0,l1));
            split4(v1,h0,h1,l0,l1);
            lacc[1] = mfma3(lacc[1], Ah, Al, mkfrag(h0,h1), mkfrag(l0,l1));
        }
        #pragma unroll
        for (int Nj = 0; Nj < 2; ++Nj) {
            f4 v = lacc[Nj];
            float mx = fmaxf(fmaxf(v.x,v.y), fmaxf(v.z,v.w));
            mx = fmaxf(mx, __shfl_xor(mx, 16));
            mx = fmaxf(mx, __shfl_xor(mx, 32));
            float e0 = __expf(v.x-mx), e1 = __expf(v.y-mx);
            float e2 = __expf(v.z-mx), e3 = __expf(v.w-mx);
            float s = e0+e1+e2+e3;
            s += __shfl_xor(s, 16);
            s += __shfl_xor(s, 32);
            float rs = 1.f / s;
            int base = WSEL_OFF + (half*16 + 4*qd)*33 + Nj*16 + l15;
            smem[base + 0*33] = e0*rs;
            smem[base + 1*33] = e1*rs;
            smem[base + 2*33] = e2*rs;
            smem[base + 3*33] = e3*rs;
        }
    }
    __syncthreads();

    // out_w
    #pragma unroll
    for (int r = 0; r < 2; ++r) {
        int idx = r*512 + tid;
        int tok = idx >> 4, nvv = idx & 15;
        out_w[(size_t)(tile0+tok)*16 + nvv] =
            smem[WSEL_OFF + ((tok>>5)*16 + nvv)*33 + (tok&31)];
    }

    // ---------------- per-variable GRN chain ----------------
    #pragma unroll 1
    for (int vi = 0; vi < 4; ++vi) {
        const int n = g*4 + vi;
        unsigned fh[4][2][2], fl[4][2][2];

        // xv^T B-frags (K=16 -> one k-step)
        {
            f4 v0 = *(const f4*)(row0 + n*16 + 4*qd);
            f4 v1 = *(const f4*)(row1 + n*16 + 4*qd);
            split4(v0, fh[0][0][0], fh[0][0][1], fl[0][0][0], fl[0][0][1]);
            split4(v1, fh[0][1][0], fh[0][1][1], fl[0][1][0], fl[0][1][1]);
        }
        // t^T = Wt^T @ xv^T + bt
        f4 tacc[4][2]; init_bias(bt + n*DD, qd, tacc);
        #pragma unroll
        for (int Mi = 0; Mi < 4; ++Mi) {
            u4 w = wtp[(n*4+Mi)*64 + lane];
            bf8 Ah = mkfrag(w.x,w.y), Al = mkfrag(w.z,w.w);
            #pragma unroll
            for (int Nj = 0; Nj < 2; ++Nj)
                tacc[Mi][Nj] = mfma3(tacc[Mi][Nj], Ah, Al,
                                     mkfrag(fh[0][Nj][0],fh[0][Nj][1]),
                                     mkfrag(fl[0][Nj][0],fl[0][Nj][1]));
        }
        acc_to_frags(tacc, fh, fl);   // t frags

        // res^T = Wp^T @ t^T + bp  -> LDS scratch
        {
            f4 racc[4][2]; init_bias(bp + n*DD, qd, racc);
            run_stage(bigp + (n*4 + 0)*16*64, lane, fh, fl, racc);
            #pragma unroll
            for (int Mi = 0; Mi < 4; ++Mi)
                #pragma unroll
                for (int Nj = 0; Nj < 2; ++Nj) {
                    int i = resbase + lane*34 + (Mi*2+Nj)*4;
                    f2 pa; pa.x = racc[Mi][Nj].x; pa.y = racc[Mi][Nj].y;
                    f2 pb; pb.x = racc[Mi][Nj].z; pb.y = racc[Mi][Nj].w;
                    *(f2*)&smem[i]   = pa;
                    *(f2*)&smem[i+2] = pb;
                }
        }
        // a = t + cproj (fp32 exact), re-split
        #pragma unroll
        for (int Mi = 0; Mi < 4; ++Mi) {
            f4 cp = *(const f4*)(cproj + (size_t)(b*NVAR+n)*DD + 16*Mi + 4*qd);
            tacc[Mi][0] += cp; tacc[Mi][1] += cp;
        }
        acc_to_frags(tacc, fh, fl);   // a frags

        // h1 = elu(W1^T @ a + b1)
        f4 hacc[4][2]; init_bias(b1 + n*DD, qd, hacc);
        run_stage(bigp + (n*4 + 1)*16*64, lane, fh, fl, hacc);
        #pragma unroll
        for (int Mi = 0; Mi < 4; ++Mi)
            #pragma unroll
            for (int Nj = 0; Nj < 2; ++Nj) {
                f4& v = hacc[Mi][Nj];
                v.x = v.x > 0.f ? v.x : (__expf(v.x)-1.f);
                v.y = v.y > 0.f ? v.y : (__expf(v.y)-1.f);
                v.z = v.z > 0.f ? v.z : (__expf(v.z)-1.f);
                v.w = v.w > 0.f ? v.w : (__expf(v.w)-1.f);
            }
        acc_to_frags(hacc, fh, fl);   // h1 frags

        // h2 = W2^T @ h1 + b2
        init_bias(b2 + n*DD, qd, hacc);
        run_stage(bigp + (n*4 + 2)*16*64, lane, fh, fl, hacc);
        acc_to_frags(hacc, fh, fl);   // h2 frags (h2 fp32 recon from hi+lo later)

        // gate logits = Wg^T @ h2 + bg
        f4 gacc[4][2]; init_bias(bg + n*DD, qd, gacc);
        run_stage(bigp + (n*4 + 3)*16*64, lane, fh, fl, gacc);

        // selection weights for this var at my token columns
        float wn0 = smem[WSEL_OFF + (half*16 + n)*33 + l15];
        float wn1 = smem[WSEL_OFF + (half*16 + n)*33 + 16 + l15];

        // z = sigmoid(g)*h2 + res
        f4 z[4][2];
        #pragma unroll
        for (int Mi = 0; Mi < 4; ++Mi)
            #pragma unroll
            for (int Nj = 0; Nj < 2; ++Nj) {
                int i = resbase + lane*34 + (Mi*2+Nj)*4;
                f2 ra = *(f2*)&smem[i];
                f2 rb = *(f2*)&smem[i+2];
                unsigned hw0 = fh[Mi][Nj][0], hw1 = fh[Mi][Nj][1];
                unsigned lw0 = fl[Mi][Nj][0], lw1 = fl[Mi][Nj][1];
                float h2x = bflo(hw0) + bflo(lw0);
                float h2y = bfhi(hw0) + bfhi(lw0);
                float h2z = bflo(hw1) + bflo(lw1);
                float h2w = bfhi(hw1) + bfhi(lw1);
                f4 gv = gacc[Mi][Nj];
                float sx = 1.f/(1.f+__expf(-gv.x));
                float sy = 1.f/(1.f+__expf(-gv.y));
                float sz = 1.f/(1.f+__expf(-gv.z));
                float sw = 1.f/(1.f+__expf(-gv.w));
                z[Mi][Nj].x = sx*h2x + ra.x;
                z[Mi][Nj].y = sy*h2y + ra.y;
                z[Mi][Nj].z = sz*h2z + rb.x;
                z[Mi][Nj].w = sw*h2w + rb.y;
            }
        // LayerNorm over d (in-lane 16 + cross-quad butterfly)
        float mu[2], rstd[2];
        #pragma unroll
        for (int Nj = 0; Nj < 2; ++Nj) {
            float s = 0.f;
            #pragma unroll
            for (int Mi = 0; Mi < 4; ++Mi)
                s += z[Mi][Nj].x + z[Mi][Nj].y + z[Mi][Nj].z + z[Mi][Nj].w;
            s += __shfl_xor(s, 16);
            s += __shfl_xor(s, 32);
            mu[Nj] = s * (1.f/64.f);
            float q = 0.f;
            #pragma unroll
            for (int Mi = 0; Mi < 4; ++Mi) {
                float dx = z[Mi][Nj].x - mu[Nj]; q += dx*dx;
                dx = z[Mi][Nj].y - mu[Nj]; q += dx*dx;
                dx = z[Mi][Nj].z - mu[Nj]; q += dx*dx;
                dx = z[Mi][Nj].w - mu[Nj]; q += dx*dx;
            }
            q += __shfl_xor(q, 16);
            q += __shfl_xor(q, 32);
            rstd[Nj] = rsqrtf(q*(1.f/64.f) + LN_EPS);
        }
        // y = LN(z)*gamma+beta ; sel += wn*y
        #pragma unroll
        for (int Mi = 0; Mi < 4; ++Mi) {
            f4 gm = *(const f4*)(gamma_ + n*DD + 16*Mi + 4*qd);
            f4 bb = *(const f4*)(beta_  + n*DD + 16*Mi + 4*qd);
            int d0 = 16*Mi + 4*qd;
            #pragma unroll
            for (int Nj = 0; Nj < 2; ++Nj) {
                float wn = Nj ? wn1 : wn0;
                int tok32 = Nj*16 + l15;
                f4 zv = z[Mi][Nj];
                atomicAdd(&smem[selbase + (d0+0)*33 + tok32],
                          wn*((zv.x-mu[Nj])*rstd[Nj]*gm.x + bb.x));
                atomicAdd(&smem[selbase + (d0+1)*33 + tok32],
                          wn*((zv.y-mu[Nj])*rstd[Nj]*gm.y + bb.y));
                atomicAdd(&smem[selbase + (d0+2)*33 + tok32],
                          wn*((zv.z-mu[Nj])*rstd[Nj]*gm.z + bb.z));
                atomicAdd(&smem[selbase + (d0+3)*33 + tok32],
                          wn*((zv.w-mu[Nj])*rstd[Nj]*gm.w + bb.w));
            }
        }
    }
    __syncthreads();

    // out_sel: thread -> (tok = tid>>3, d-block = (tid&7)*8)
    {
        int tok = tid >> 3;
        int d0 = (tid & 7) * 8;
        int sb = SEL_OFF + (tok>>5)*2112 + (tok&31);
        f4 o0, o1;
        o0.x = smem[sb + (d0+0)*33]; o0.y = smem[sb + (d0+1)*33];
        o0.z = smem[sb + (d0+2)*33]; o0.w = smem[sb + (d0+3)*33];
        o1.x = smem[sb + (d0+4)*33]; o1.y = smem[sb + (d0+5)*33];
        o1.z = smem[sb + (d0+6)*33]; o1.w = smem[sb + (d0+7)*33];
        float* po = out_sel + (size_t)(tile0+tok)*DD + d0;
        *(f4*)po = o0;
        *(f4*)(po+4) = o1;
    }
}

extern "C" void kernel_launch(void* const* d_in, const int* in_sizes, int n_in,
                              void* d_out, int out_size, void* d_ws, size_t ws_size,
                              hipStream_t stream) {
    const float* inp  = (const float*)d_in[0];
    const float* ctx  = (const float*)d_in[1];
    const float* Wt   = (const float*)d_in[2];
    const float* bt   = (const float*)d_in[3];
    const float* Wctx = (const float*)d_in[4];
    const float* W1   = (const float*)d_in[5];
    const float* b1   = (const float*)d_in[6];
    const float* W2   = (const float*)d_in[7];
    const float* b2   = (const float*)d_in[8];
    const float* Wg   = (const float*)d_in[9];
    const float* bg   = (const float*)d_in[10];
    const float* Wp   = (const float*)d_in[11];
    const float* bp   = (const float*)d_in[12];
    const float* gm   = (const float*)d_in[13];
    const float* bt2  = (const float*)d_in[14];
    const float* Ws   = (const float*)d_in[15];
    const float* bs   = (const float*)d_in[16];

    float* out_sel = (float*)d_out;
    float* out_w   = out_sel + (size_t)BT * DD;

    char* ws = (char*)d_ws;
    float* cproj = (float*)(ws + CPROJ_OFF);
    u4* wtp  = (u4*)(ws + WTP_OFF);
    u4* bigp = (u4*)(ws + BIGP_OFF);
    u4* wsp  = (u4*)(ws + WSP_OFF);

    pack_kernel<<<276, 256, 0, stream>>>(Wt, W1, W2, Wg, Wp, Ws, wtp, bigp, wsp);
    cproj_kernel<<<NB * NVAR, DD, 0, stream>>>(ctx, Wctx, cproj);
    vsn_kernel<<<BT / 64, 512, 0, stream>>>(inp, wtp, bigp, wsp,
                                            bt, b1, b2, bg, bp, gm, bt2, bs,
                                            cproj, out_sel, out_w);
}

// Round 6
// 315.461 us; speedup vs baseline: 4.0098x; 1.1152x over previous
//
#include <hip/hip_runtime.h>
#include <math.h>

#define NB 64
#define NT 512
#define NVAR 16
#define VDIM 16
#define DD 64
#define FF 256
#define BT (NB*NT)
#define LN_EPS 1e-3f

typedef __attribute__((ext_vector_type(8))) short bf8;   // 8 bf16 = one MFMA A/B operand
typedef __attribute__((ext_vector_type(4))) float f4;
typedef __attribute__((ext_vector_type(4))) int i4;
typedef __attribute__((ext_vector_type(4))) unsigned u4;

// ---- ws layout (bytes) ----
#define CPROJ_OFF   0
#define WTP_OFF     262144                 // 16 vars x 4 frags x 64 lanes x 16B = 64KB
#define BIGP_OFF    (262144+65536)         // 16 vars x 4 mats x 16 frags x 64 x 16B = 1MB
#define WSP_OFF     (262144+65536+1048576) // 16 frags x 64 x 16B = 16KB
// mats: 0=Wp 1=W1 2=W2 3=Wg

// RNE fp32 -> bf16 split helpers. hi = RNE(x); lo = x - hi (RNE'd when packed).
__device__ __forceinline__ void split1(float x, unsigned &hb, float &lo) {
    unsigned u = __builtin_bit_cast(unsigned, x);
    unsigned r = u + 0x7fffu + ((u >> 16) & 1u);
    hb = r >> 16;
    lo = x - __builtin_bit_cast(float, r & 0xffff0000u);
}
__device__ __forceinline__ unsigned rnepk(float x, float y) {
    unsigned a = __builtin_bit_cast(unsigned, x);
    unsigned b = __builtin_bit_cast(unsigned, y);
    a = a + 0x7fffu + ((a >> 16) & 1u);
    b = b + 0x7fffu + ((b >> 16) & 1u);
    return (a >> 16) | (b & 0xffff0000u);
}
__device__ __forceinline__ void split4(f4 v, unsigned &h0, unsigned &h1,
                                       unsigned &l0, unsigned &l1) {
    unsigned b0,b1,b2,b3; float q0,q1,q2,q3;
    split1(v.x,b0,q0); split1(v.y,b1,q1); split1(v.z,b2,q2); split1(v.w,b3,q3);
    h0 = b0 | (b1<<16); h1 = b2 | (b3<<16);
    l0 = rnepk(q0,q1); l1 = rnepk(q2,q3);
}
__device__ __forceinline__ bf8 mkfrag(unsigned w0, unsigned w1) {
    i4 t; t.x = (int)w0; t.y = (int)w1; t.z = 0; t.w = 0;  // k-slots 4..7 zero
    return __builtin_bit_cast(bf8, t);
}
__device__ __forceinline__ float bflo(unsigned w){ return __builtin_bit_cast(float, w<<16); }
__device__ __forceinline__ float bfhi(unsigned w){ return __builtin_bit_cast(float, w & 0xffff0000u); }

__device__ __forceinline__ f4 mfma3(f4 acc, bf8 Ah, bf8 Al, bf8 Bh, bf8 Bl) {
    acc = __builtin_amdgcn_mfma_f32_16x16x32_bf16(Ah, Bh, acc, 0,0,0);
    acc = __builtin_amdgcn_mfma_f32_16x16x32_bf16(Ah, Bl, acc, 0,0,0);
    acc = __builtin_amdgcn_mfma_f32_16x16x32_bf16(Al, Bh, acc, 0,0,0);
    return acc;
}

// acc (C-layout) -> B-operand frags of the next stage (pure in-lane repack)
__device__ __forceinline__ void acc_to_frags1(const f4 acc[4],
        unsigned fh[4][2], unsigned fl[4][2]) {
    #pragma unroll
    for (int Ks = 0; Ks < 4; ++Ks)
        split4(acc[Ks], fh[Ks][0], fh[Ks][1], fl[Ks][0], fl[Ks][1]);
}
// One 64x64 GEMM-stage (Nj=1): acc[Mi] += Wpack^T . Bfrags  (3-product split)
__device__ __forceinline__ void run_stage1(const u4* __restrict__ ap, int lane,
        const unsigned fh[4][2], const unsigned fl[4][2], f4 acc[4]) {
    u4 wcur[4], wnxt[4];
    #pragma unroll
    for (int Mi = 0; Mi < 4; ++Mi) wcur[Mi] = ap[Mi*64 + lane];
    #pragma unroll
    for (int Ks = 0; Ks < 4; ++Ks) {
        int Kn = (Ks < 3) ? (Ks + 1) : 0;        // last-iter prefetch: harmless re-read
        #pragma unroll
        for (int Mi = 0; Mi < 4; ++Mi) wnxt[Mi] = ap[(Kn*4+Mi)*64 + lane];
        bf8 Bh = mkfrag(fh[Ks][0], fh[Ks][1]);
        bf8 Bl = mkfrag(fl[Ks][0], fl[Ks][1]);
        #pragma unroll
        for (int Mi = 0; Mi < 4; ++Mi) {
            bf8 Ah = mkfrag(wcur[Mi].x, wcur[Mi].y);
            bf8 Al = mkfrag(wcur[Mi].z, wcur[Mi].w);
            acc[Mi] = mfma3(acc[Mi], Ah, Al, Bh, Bl);
        }
        #pragma unroll
        for (int Mi = 0; Mi < 4; ++Mi) wcur[Mi] = wnxt[Mi];
    }
}

// Prep: weight pack (blocks 0..275) + cproj (blocks 276..531), one launch.
// A^T frag (Mi,Ks): lane L holds W[k=16Ks+4(L>>4)+j][m=16Mi+(L&15)], j=0..3.
__global__ void prep_kernel(const float* __restrict__ Wt, const float* __restrict__ W1,
                            const float* __restrict__ W2, const float* __restrict__ Wg,
                            const float* __restrict__ Wp, const float* __restrict__ Ws,
                            const float* __restrict__ ctx, const float* __restrict__ Wctx,
                            u4* __restrict__ wtp, u4* __restrict__ bigp,
                            u4* __restrict__ wsp, float* __restrict__ cproj) {
    if (blockIdx.x >= 276) {
        int bn = (blockIdx.x - 276) * 4 + (threadIdx.x >> 6);
        int b = bn >> 4, n = bn & 15;
        int d = threadIdx.x & 63;
        const float* __restrict__ w = Wctx + n * DD * DD;
        const float* __restrict__ c = ctx + b * DD;
        float acc = 0.f;
        #pragma unroll 8
        for (int k = 0; k < DD; ++k) acc += c[k] * w[k * DD + d];
        cproj[bn * DD + d] = acc;
        return;
    }
    int t = blockIdx.x * 256 + threadIdx.x;
    float v0, v1, v2, v3; u4* dst;
    if (t < 65536) {
        int lane = t & 63, Mi = (t>>6)&3, Ks = (t>>8)&3, mat = (t>>10)&3, var = t>>12;
        const float* W = (mat==0) ? Wp : (mat==1) ? W1 : (mat==2) ? W2 : Wg;
        const float* src = W + var*4096;
        int m = 16*Mi + (lane&15), k0 = 16*Ks + 4*(lane>>4);
        v0 = src[(k0+0)*64+m]; v1 = src[(k0+1)*64+m];
        v2 = src[(k0+2)*64+m]; v3 = src[(k0+3)*64+m];
        dst = bigp + ((var*4+mat)*16 + Ks*4 + Mi)*64 + lane;
    } else if (t < 65536+4096) {
        int r = t - 65536;
        int lane = r & 63, Mi = (r>>6)&3, var = r>>8;
        int m = 16*Mi + (lane&15), k0 = 4*(lane>>4);
        const float* src = Wt + var*1024;
        v0 = src[(k0+0)*64+m]; v1 = src[(k0+1)*64+m];
        v2 = src[(k0+2)*64+m]; v3 = src[(k0+3)*64+m];
        dst = wtp + (var*4+Mi)*64 + lane;
    } else if (t < 65536+4096+1024) {
        int r = t - 69632;
        int lane = r & 63, Ks = r >> 6;
        int m = lane & 15, k0 = 16*Ks + 4*(lane>>4);
        v0 = Ws[(k0+0)*16+m]; v1 = Ws[(k0+1)*16+m];
        v2 = Ws[(k0+2)*16+m]; v3 = Ws[(k0+3)*16+m];
        dst = wsp + Ks*64 + lane;
    } else return;
    f4 v; v.x=v0; v.y=v1; v.z=v2; v.w=v3;
    unsigned h0,h1,l0,l1; split4(v,h0,h1,l0,l1);
    u4 o; o.x=h0; o.y=h1; o.z=l0; o.w=l1;
    *dst = o;
}

// Main: block = 256 threads = 4 waves, 32 tokens.
// wave wv: tokhalf = wv>>1 (16 tokens), grp = wv&1 (vars 8*grp..8*grp+7).
// All activations transposed (d on M, tok on N=16): C-regs of one stage ARE the
// next stage's B-operand (in-lane bf16 split; logical k 4-per-quad in slots 0..3).
// res + selection partial live in REGISTERS (no big LDS -> 4 waves/SIMD).
// PSEL row stride = 72 dw (288B = 18x16B) so every f4 slot is 16B-aligned
// (stride 69 in R5 mis-aligned ds_*_b128 -> corrupt data on odd rows).
#define PSEL_OFF 0          // 64 rows x 72 = 4608 dw (rows: grp*32 + tokhalf*16 + l15)
#define WSEL_OFF 4608       // 2 tokhalf x 16 n x 17 = 544 dw
#define SMEM_DW  5152       // 20608 B

__global__ __launch_bounds__(256, 4)
void vsn_kernel(const float* __restrict__ inp,
                const u4* __restrict__ wtp, const u4* __restrict__ bigp,
                const u4* __restrict__ wsp,
                const float* __restrict__ bt, const float* __restrict__ b1,
                const float* __restrict__ b2, const float* __restrict__ bg,
                const float* __restrict__ bp,
                const float* __restrict__ gamma_, const float* __restrict__ beta_,
                const float* __restrict__ bs,
                const float* __restrict__ cproj,
                float* __restrict__ out_sel, float* __restrict__ out_w) {
    __shared__ float smem[SMEM_DW];

    const int tid  = threadIdx.x;
    const int lane = tid & 63;
    const int wv   = tid >> 6;
    const int tokhalf = wv >> 1;
    const int grp  = wv & 1;
    const int qd   = lane >> 4;
    const int l15  = lane & 15;
    const int tile0 = blockIdx.x * 32;
    const int b     = blockIdx.x >> 4;          // tile0 / NT
    const int tok0  = tile0 + tokhalf * 16;

    const float* row = inp + (size_t)(tok0 + l15) * FF;   // my token's feature row

    // ---------------- logits via MFMA + softmax (per wave, 16 tokens) -------
    {
        f4 lacc = *(const f4*)(bs + 4*qd);      // n = 4*qd + reg
        #pragma unroll
        for (int Ks = 0; Ks < 16; ++Ks) {
            u4 w = wsp[Ks*64 + lane];
            bf8 Ah = mkfrag(w.x, w.y), Al = mkfrag(w.z, w.w);
            f4 v = *(const f4*)(row + 16*Ks + 4*qd);
            unsigned h0,h1,l0,l1;
            split4(v,h0,h1,l0,l1);
            lacc = mfma3(lacc, Ah, Al, mkfrag(h0,h1), mkfrag(l0,l1));
        }
        float mx = fmaxf(fmaxf(lacc.x,lacc.y), fmaxf(lacc.z,lacc.w));
        mx = fmaxf(mx, __shfl_xor(mx, 16));
        mx = fmaxf(mx, __shfl_xor(mx, 32));
        float e0 = __expf(lacc.x-mx), e1 = __expf(lacc.y-mx);
        float e2 = __expf(lacc.z-mx), e3 = __expf(lacc.w-mx);
        float s = e0+e1+e2+e3;
        s += __shfl_xor(s, 16);
        s += __shfl_xor(s, 32);
        float rs = 1.f / s;
        e0 *= rs; e1 *= rs; e2 *= rs; e3 *= rs;
        // wave-local wsel (each wave writes the full set for its tokhalf;
        // it reads only what it wrote; the grp-pair writes identical bits)
        int base = WSEL_OFF + tokhalf*272 + (4*qd)*17 + l15;
        smem[base + 0*17] = e0;
        smem[base + 1*17] = e1;
        smem[base + 2*17] = e2;
        smem[base + 3*17] = e3;
        if (grp == 0) {
            f4 o; o.x=e0; o.y=e1; o.z=e2; o.w=e3;
            *(f4*)(out_w + (size_t)(tok0 + l15)*16 + 4*qd) = o;
        }
    }

    // ---------------- per-variable GRN chain (8 vars per wave) --------------
    f4 sel[4];
    #pragma unroll
    for (int Mi = 0; Mi < 4; ++Mi) sel[Mi] = (f4)0.f;

    #pragma unroll 1
    for (int vi = 0; vi < 8; ++vi) {
        const int n = grp*8 + vi;
        unsigned fh[4][2], fl[4][2];

        // xv^T B-frag (K=16 -> single k-step)
        {
            f4 v = *(const f4*)(row + n*16 + 4*qd);
            split4(v, fh[0][0], fh[0][1], fl[0][0], fl[0][1]);
        }
        // t^T = Wt^T @ xv^T + bt
        f4 tacc[4];
        #pragma unroll
        for (int Mi = 0; Mi < 4; ++Mi) tacc[Mi] = *(const f4*)(bt + n*DD + 16*Mi + 4*qd);
        {
            bf8 Bh = mkfrag(fh[0][0], fh[0][1]);
            bf8 Bl = mkfrag(fl[0][0], fl[0][1]);
            #pragma unroll
            for (int Mi = 0; Mi < 4; ++Mi) {
                u4 w = wtp[(n*4+Mi)*64 + lane];
                tacc[Mi] = mfma3(tacc[Mi], mkfrag(w.x,w.y), mkfrag(w.z,w.w), Bh, Bl);
            }
        }
        acc_to_frags1(tacc, fh, fl);   // t frags

        // res^T = Wp^T @ t^T + bp  (REGISTERS)
        f4 racc[4];
        #pragma unroll
        for (int Mi = 0; Mi < 4; ++Mi) racc[Mi] = *(const f4*)(bp + n*DD + 16*Mi + 4*qd);
        run_stage1(bigp + (n*4 + 0)*16*64, lane, fh, fl, racc);

        // a = t + cproj (fp32 exact), re-split
        #pragma unroll
        for (int Mi = 0; Mi < 4; ++Mi)
            tacc[Mi] += *(const f4*)(cproj + (size_t)(b*NVAR+n)*DD + 16*Mi + 4*qd);
        acc_to_frags1(tacc, fh, fl);   // a frags

        // h1 = elu(W1^T @ a + b1)
        f4 hacc[4];
        #pragma unroll
        for (int Mi = 0; Mi < 4; ++Mi) hacc[Mi] = *(const f4*)(b1 + n*DD + 16*Mi + 4*qd);
        run_stage1(bigp + (n*4 + 1)*16*64, lane, fh, fl, hacc);
        #pragma unroll
        for (int Mi = 0; Mi < 4; ++Mi) {
            f4& v = hacc[Mi];
            v.x = v.x > 0.f ? v.x : (__expf(v.x)-1.f);
            v.y = v.y > 0.f ? v.y : (__expf(v.y)-1.f);
            v.z = v.z > 0.f ? v.z : (__expf(v.z)-1.f);
            v.w = v.w > 0.f ? v.w : (__expf(v.w)-1.f);
        }
        acc_to_frags1(hacc, fh, fl);   // h1 frags

        // h2 = W2^T @ h1 + b2
        #pragma unroll
        for (int Mi = 0; Mi < 4; ++Mi) hacc[Mi] = *(const f4*)(b2 + n*DD + 16*Mi + 4*qd);
        run_stage1(bigp + (n*4 + 2)*16*64, lane, fh, fl, hacc);
        acc_to_frags1(hacc, fh, fl);   // h2 frags (fp32 recon from hi+lo below)

        // gate logits = Wg^T @ h2 + bg
        f4 gacc[4];
        #pragma unroll
        for (int Mi = 0; Mi < 4; ++Mi) gacc[Mi] = *(const f4*)(bg + n*DD + 16*Mi + 4*qd);
        run_stage1(bigp + (n*4 + 3)*16*64, lane, fh, fl, gacc);

        // z = sigmoid(g)*h2 + res
        f4 z[4];
        #pragma unroll
        for (int Mi = 0; Mi < 4; ++Mi) {
            float h2x = bflo(fh[Mi][0]) + bflo(fl[Mi][0]);
            float h2y = bfhi(fh[Mi][0]) + bfhi(fl[Mi][0]);
            float h2z = bflo(fh[Mi][1]) + bflo(fl[Mi][1]);
            float h2w = bfhi(fh[Mi][1]) + bfhi(fl[Mi][1]);
            f4 gv = gacc[Mi];
            z[Mi].x = h2x / (1.f+__expf(-gv.x)) + racc[Mi].x;
            z[Mi].y = h2y / (1.f+__expf(-gv.y)) + racc[Mi].y;
            z[Mi].z = h2z / (1.f+__expf(-gv.z)) + racc[Mi].z;
            z[Mi].w = h2w / (1.f+__expf(-gv.w)) + racc[Mi].w;
        }
        // LayerNorm over d (16 in-lane + cross-quad butterfly)
        float s = 0.f;
        #pragma unroll
        for (int Mi = 0; Mi < 4; ++Mi) s += z[Mi].x + z[Mi].y + z[Mi].z + z[Mi].w;
        s += __shfl_xor(s, 16);
        s += __shfl_xor(s, 32);
        float mu = s * (1.f/64.f);
        float q = 0.f;
        #pragma unroll
        for (int Mi = 0; Mi < 4; ++Mi) {
            float dx = z[Mi].x - mu; q += dx*dx;
            dx = z[Mi].y - mu; q += dx*dx;
            dx = z[Mi].z - mu; q += dx*dx;
            dx = z[Mi].w - mu; q += dx*dx;
        }
        q += __shfl_xor(q, 16);
        q += __shfl_xor(q, 32);
        float rstd = rsqrtf(q*(1.f/64.f) + LN_EPS);

        float wn = smem[WSEL_OFF + tokhalf*272 + n*17 + l15];
        #pragma unroll
        for (int Mi = 0; Mi < 4; ++Mi) {
            f4 gm = *(const f4*)(gamma_ + n*DD + 16*Mi + 4*qd);
            f4 bb = *(const f4*)(beta_  + n*DD + 16*Mi + 4*qd);
            sel[Mi].x += wn*((z[Mi].x-mu)*rstd*gm.x + bb.x);
            sel[Mi].y += wn*((z[Mi].y-mu)*rstd*gm.y + bb.y);
            sel[Mi].z += wn*((z[Mi].z-mu)*rstd*gm.z + bb.z);
            sel[Mi].w += wn*((z[Mi].w-mu)*rstd*gm.w + bb.w);
        }
    }

    // partial sel -> LDS row (grp*32 + tokhalf*16 + l15), then cross-grp reduce
    {
        int base = PSEL_OFF + (grp*32 + tokhalf*16 + l15)*72;
        #pragma unroll
        for (int Mi = 0; Mi < 4; ++Mi)
            *(f4*)&smem[base + 16*Mi + 4*qd] = sel[Mi];
    }
    __syncthreads();
    {
        int tokloc = tid >> 3;            // 0..31 (exactly the 32 tokens of this tile)
        int d0 = (tid & 7) * 8;
        int rbase = PSEL_OFF + tokloc*72 + d0;
        f4 a0 = *(f4*)&smem[rbase];
        f4 a1 = *(f4*)&smem[rbase + 4];
        f4 b0 = *(f4*)&smem[rbase + 32*72];
        f4 b1v = *(f4*)&smem[rbase + 32*72 + 4];
        float* po = out_sel + (size_t)(tile0+tokloc)*DD + d0;
        *(f4*)po     = a0 + b0;
        *(f4*)(po+4) = a1 + b1v;
    }
}

extern "C" void kernel_launch(void* const* d_in, const int* in_sizes, int n_in,
                              void* d_out, int out_size, void* d_ws, size_t ws_size,
                              hipStream_t stream) {
    const float* inp  = (const float*)d_in[0];
    const float* ctx  = (const float*)d_in[1];
    const float* Wt   = (const float*)d_in[2];
    const float* bt   = (const float*)d_in[3];
    const float* Wctx = (const float*)d_in[4];
    const float* W1   = (const float*)d_in[5];
    const float* b1   = (const float*)d_in[6];
    const float* W2   = (const float*)d_in[7];
    const float* b2   = (const float*)d_in[8];
    const float* Wg   = (const float*)d_in[9];
    const float* bg   = (const float*)d_in[10];
    const float* Wp   = (const float*)d_in[11];
    const float* bp   = (const float*)d_in[12];
    const float* gm   = (const float*)d_in[13];
    const float* bt2  = (const float*)d_in[14];
    const float* Ws   = (const float*)d_in[15];
    const float* bs   = (const float*)d_in[16];

    float* out_sel = (float*)d_out;
    float* out_w   = out_sel + (size_t)BT * DD;

    char* ws = (char*)d_ws;
    float* cproj = (float*)(ws + CPROJ_OFF);
    u4* wtp  = (u4*)(ws + WTP_OFF);
    u4* bigp = (u4*)(ws + BIGP_OFF);
    u4* wsp  = (u4*)(ws + WSP_OFF);

    prep_kernel<<<532, 256, 0, stream>>>(Wt, W1, W2, Wg, Wp, Ws, ctx, Wctx,
                                         wtp, bigp, wsp, cproj);
    vsn_kernel<<<BT / 32, 256, 0, stream>>>(inp, wtp, bigp, wsp,
                                            bt, b1, b2, bg, bp, gm, bt2, bs,
                                            cproj, out_sel, out_w);
}

// Round 7
// 260.392 us; speedup vs baseline: 4.8578x; 1.2115x over previous
//
#include <hip/hip_runtime.h>
#include <math.h>

#define NB 64
#define NT 512
#define NVAR 16
#define VDIM 16
#define DD 64
#define FF 256
#define BT (NB*NT)
#define LN_EPS 1e-3f

typedef __attribute__((ext_vector_type(8))) short bf8;   // 8 bf16 = one MFMA A/B operand
typedef __attribute__((ext_vector_type(4))) float f4;
typedef __attribute__((ext_vector_type(4))) int i4;
typedef __attribute__((ext_vector_type(4))) unsigned u4;

// ---- ws layout (bytes) ----
#define CPROJ_OFF   0                        // 64*16*64 f32 = 256KB
#define RBIAS_OFF   262144                   // 64*16*64 f32 = 256KB  (bp - cproj@Wp)
#define WTP_OFF     524288                   // 16 vars x 4 frags x 64 x 16B = 64KB
#define BIGP_OFF    (524288+65536)           // 16 vars x 4 mats x 16 frags x 64 x 16B = 1MB
#define WSP_OFF     (524288+65536+1048576)   // 16 frags x 64 x 16B = 16KB
// mats: 0=Wp 1=W1 2=W2 3=Wg

// RNE fp32 -> bf16 split helpers. hi = RNE(x); lo = x - hi (RNE'd when packed).
__device__ __forceinline__ void split1(float x, unsigned &hb, float &lo) {
    unsigned u = __builtin_bit_cast(unsigned, x);
    unsigned r = u + 0x7fffu + ((u >> 16) & 1u);
    hb = r >> 16;
    lo = x - __builtin_bit_cast(float, r & 0xffff0000u);
}
__device__ __forceinline__ unsigned rnepk(float x, float y) {
    unsigned a = __builtin_bit_cast(unsigned, x);
    unsigned b = __builtin_bit_cast(unsigned, y);
    a = a + 0x7fffu + ((a >> 16) & 1u);
    b = b + 0x7fffu + ((b >> 16) & 1u);
    return (a >> 16) | (b & 0xffff0000u);
}
__device__ __forceinline__ void split4(f4 v, unsigned &h0, unsigned &h1,
                                       unsigned &l0, unsigned &l1) {
    unsigned b0,b1,b2,b3; float q0,q1,q2,q3;
    split1(v.x,b0,q0); split1(v.y,b1,q1); split1(v.z,b2,q2); split1(v.w,b3,q3);
    h0 = b0 | (b1<<16); h1 = b2 | (b3<<16);
    l0 = rnepk(q0,q1); l1 = rnepk(q2,q3);
}
// A operand = packed u4 verbatim: slots 0..3 = W_hi, slots 4..7 = W_lo
__device__ __forceinline__ bf8 afrag(u4 w) { return __builtin_bit_cast(bf8, w); }
// B operands for the 2-mfma split: [x_h|x_h] and [x_l|0]
__device__ __forceinline__ bf8 mk_bhh(unsigned h0, unsigned h1) {
    i4 t; t.x = (int)h0; t.y = (int)h1; t.z = (int)h0; t.w = (int)h1;
    return __builtin_bit_cast(bf8, t);
}
__device__ __forceinline__ bf8 mk_bl0(unsigned l0, unsigned l1) {
    i4 t; t.x = (int)l0; t.y = (int)l1; t.z = 0; t.w = 0;
    return __builtin_bit_cast(bf8, t);
}
__device__ __forceinline__ float bflo(unsigned w){ return __builtin_bit_cast(float, w<<16); }
__device__ __forceinline__ float bfhi(unsigned w){ return __builtin_bit_cast(float, w & 0xffff0000u); }

// 2-mfma split: A=[Wh|Wl] with Bh=[xh|xh] gives Wh*xh + Wl*xh; Bl=[xl|0] adds Wh*xl.
__device__ __forceinline__ f4 mfma2(f4 acc, bf8 Af, bf8 Bh, bf8 Bl) {
    acc = __builtin_amdgcn_mfma_f32_16x16x32_bf16(Af, Bh, acc, 0,0,0);
    acc = __builtin_amdgcn_mfma_f32_16x16x32_bf16(Af, Bl, acc, 0,0,0);
    return acc;
}

// acc (C-layout) -> B-operand frags of the next stage (pure in-lane repack)
__device__ __forceinline__ void acc_to_frags1(const f4 acc[4],
        unsigned fh[4][2], unsigned fl[4][2]) {
    #pragma unroll
    for (int Ks = 0; Ks < 4; ++Ks)
        split4(acc[Ks], fh[Ks][0], fh[Ks][1], fl[Ks][0], fl[Ks][1]);
}
// One 64x64 GEMM-stage: acc[Mi] += Wpack^T . Bfrags  (2-mfma split)
__device__ __forceinline__ void run_stage2(const u4* __restrict__ ap, int lane,
        const unsigned fh[4][2], const unsigned fl[4][2], f4 acc[4]) {
    #pragma unroll 2
    for (int Ks = 0; Ks < 4; ++Ks) {
        bf8 Bh = mk_bhh(fh[Ks][0], fh[Ks][1]);
        bf8 Bl = mk_bl0(fl[Ks][0], fl[Ks][1]);
        #pragma unroll
        for (int Mi = 0; Mi < 4; ++Mi) {
            u4 w = ap[(Ks*4+Mi)*64 + lane];
            acc[Mi] = mfma2(acc[Mi], afrag(w), Bh, Bl);
        }
    }
}

// Prep: weight pack (blocks 0..275) + cproj (blocks 276..531), one launch.
// A^T frag (Mi,Ks): lane L holds W[k=16Ks+4(L>>4)+j][m=16Mi+(L&15)], j=0..3.
__global__ void prep_kernel(const float* __restrict__ Wt, const float* __restrict__ W1,
                            const float* __restrict__ W2, const float* __restrict__ Wg,
                            const float* __restrict__ Wp, const float* __restrict__ Ws,
                            const float* __restrict__ ctx, const float* __restrict__ Wctx,
                            u4* __restrict__ wtp, u4* __restrict__ bigp,
                            u4* __restrict__ wsp, float* __restrict__ cproj) {
    if (blockIdx.x >= 276) {
        int bn = (blockIdx.x - 276) * 4 + (threadIdx.x >> 6);
        int b = bn >> 4, n = bn & 15;
        int d = threadIdx.x & 63;
        const float* __restrict__ w = Wctx + n * DD * DD;
        const float* __restrict__ c = ctx + b * DD;
        float acc = 0.f;
        #pragma unroll 8
        for (int k = 0; k < DD; ++k) acc += c[k] * w[k * DD + d];
        cproj[bn * DD + d] = acc;
        return;
    }
    int t = blockIdx.x * 256 + threadIdx.x;
    float v0, v1, v2, v3; u4* dst;
    if (t < 65536) {
        int lane = t & 63, Mi = (t>>6)&3, Ks = (t>>8)&3, mat = (t>>10)&3, var = t>>12;
        const float* W = (mat==0) ? Wp : (mat==1) ? W1 : (mat==2) ? W2 : Wg;
        const float* src = W + var*4096;
        int m = 16*Mi + (lane&15), k0 = 16*Ks + 4*(lane>>4);
        v0 = src[(k0+0)*64+m]; v1 = src[(k0+1)*64+m];
        v2 = src[(k0+2)*64+m]; v3 = src[(k0+3)*64+m];
        dst = bigp + ((var*4+mat)*16 + Ks*4 + Mi)*64 + lane;
    } else if (t < 65536+4096) {
        int r = t - 65536;
        int lane = r & 63, Mi = (r>>6)&3, var = r>>8;
        int m = 16*Mi + (lane&15), k0 = 4*(lane>>4);
        const float* src = Wt + var*1024;
        v0 = src[(k0+0)*64+m]; v1 = src[(k0+1)*64+m];
        v2 = src[(k0+2)*64+m]; v3 = src[(k0+3)*64+m];
        dst = wtp + (var*4+Mi)*64 + lane;
    } else if (t < 65536+4096+1024) {
        int r = t - 69632;
        int lane = r & 63, Ks = r >> 6;
        int m = lane & 15, k0 = 16*Ks + 4*(lane>>4);
        v0 = Ws[(k0+0)*16+m]; v1 = Ws[(k0+1)*16+m];
        v2 = Ws[(k0+2)*16+m]; v3 = Ws[(k0+3)*16+m];
        dst = wsp + Ks*64 + lane;
    } else return;
    f4 v; v.x=v0; v.y=v1; v.z=v2; v.w=v3;
    unsigned h0,h1,l0,l1; split4(v,h0,h1,l0,l1);
    u4 o; o.x=h0; o.y=h1; o.z=l0; o.w=l1;
    *dst = o;
}

// rbias[b][n][d] = bp[n][d] - sum_k cproj[b][n][k] * Wp[n][k][d]  (fp32 exact)
// Then res = Wp^T a + rbias == Wp^T t + bp, letting res & h1 share a-frags.
__global__ void rbias_kernel(const float* __restrict__ cproj,
                             const float* __restrict__ Wp,
                             const float* __restrict__ bp,
                             float* __restrict__ rbias) {
    int bn = blockIdx.x;
    int n = bn & 15;
    int d = threadIdx.x;
    const float* __restrict__ w = Wp + n * DD * DD;
    const float* __restrict__ c = cproj + bn * DD;
    float acc = bp[n * DD + d];
    #pragma unroll 8
    for (int k = 0; k < DD; ++k) acc -= c[k] * w[k * DD + d];
    rbias[bn * DD + d] = acc;
}

// Main: block = 512 threads = 8 waves, 64 tokens; grid = 512 (2 blocks/CU, full chip).
// wave wv: grp = wv&1 (vars 8*grp..8*grp+7), tq = wv>>1 (token quarter, 16 tokens).
// The 4 same-grp waves stream IDENTICAL weight addresses -> L1 reuse (8x less L2).
// All activations transposed (d on M, tok on N=16): C-regs of one stage ARE the
// next stage's B-operand (in-lane bf16 split; logical k 4-per-quad in slots 0..3;
// W_lo rides in A slots 4..7 -> 2 mfma per k-step instead of 3).
#define PSEL_OFF 0          // 128 rows (grp*64+tq*16+l15) x 68 dw = 8704 dw
#define WSEL_OFF 8704       // 4 tq x 16 n x 17 = 1088 dw
#define SMEM_DW  9792       // 39168 B

__global__ __launch_bounds__(512, 4)
void vsn_kernel(const float* __restrict__ inp,
                const u4* __restrict__ wtp, const u4* __restrict__ bigp,
                const u4* __restrict__ wsp,
                const float* __restrict__ bt, const float* __restrict__ b1,
                const float* __restrict__ b2, const float* __restrict__ bg,
                const float* __restrict__ rbias,
                const float* __restrict__ gamma_, const float* __restrict__ beta_,
                const float* __restrict__ bs,
                const float* __restrict__ cproj,
                float* __restrict__ out_sel, float* __restrict__ out_w) {
    __shared__ float smem[SMEM_DW];

    const int tid  = threadIdx.x;
    const int lane = tid & 63;
    const int wv   = tid >> 6;
    const int grp  = wv & 1;
    const int tq   = wv >> 1;
    const int qd   = lane >> 4;
    const int l15  = lane & 15;
    const int tile0 = blockIdx.x * 64;
    const int b     = blockIdx.x >> 3;          // tile0 / NT
    const int tok0  = tile0 + tq * 16;

    const float* row = inp + (size_t)(tok0 + l15) * FF;   // my token's feature row

    // ---------------- logits via MFMA + softmax (per wave, 16 tokens) -------
    {
        f4 lacc = *(const f4*)(bs + 4*qd);      // n = 4*qd + reg
        #pragma unroll 4
        for (int Ks = 0; Ks < 16; ++Ks) {
            u4 w = wsp[Ks*64 + lane];
            f4 v = *(const f4*)(row + 16*Ks + 4*qd);
            unsigned h0,h1,l0,l1;
            split4(v,h0,h1,l0,l1);
            lacc = mfma2(lacc, afrag(w), mk_bhh(h0,h1), mk_bl0(l0,l1));
        }
        float mx = fmaxf(fmaxf(lacc.x,lacc.y), fmaxf(lacc.z,lacc.w));
        mx = fmaxf(mx, __shfl_xor(mx, 16));
        mx = fmaxf(mx, __shfl_xor(mx, 32));
        float e0 = __expf(lacc.x-mx), e1 = __expf(lacc.y-mx);
        float e2 = __expf(lacc.z-mx), e3 = __expf(lacc.w-mx);
        float s = e0+e1+e2+e3;
        s += __shfl_xor(s, 16);
        s += __shfl_xor(s, 32);
        float rs = 1.f / s;
        e0 *= rs; e1 *= rs; e2 *= rs; e3 *= rs;
        // both grp waves of a tq write identical bits -> benign duplicate
        int base = WSEL_OFF + tq*272 + (4*qd)*17 + l15;
        smem[base + 0*17] = e0;
        smem[base + 1*17] = e1;
        smem[base + 2*17] = e2;
        smem[base + 3*17] = e3;
        if (grp == 0) {
            f4 o; o.x=e0; o.y=e1; o.z=e2; o.w=e3;
            *(f4*)(out_w + (size_t)(tok0 + l15)*16 + 4*qd) = o;
        }
    }

    // ---------------- per-variable GRN chain (8 vars per wave) --------------
    f4 sel[4];
    #pragma unroll
    for (int Mi = 0; Mi < 4; ++Mi) sel[Mi] = (f4)0.f;

    #pragma unroll 1
    for (int vi = 0; vi < 8; ++vi) {
        const int n = grp*8 + vi;
        unsigned fh[4][2], fl[4][2];

        // t = Wt^T @ xv + bt; a = t + cproj; a-frags feed BOTH res and h1.
        f4 tacc[4];
        #pragma unroll
        for (int Mi = 0; Mi < 4; ++Mi) tacc[Mi] = *(const f4*)(bt + n*DD + 16*Mi + 4*qd);
        {
            f4 v = *(const f4*)(row + n*16 + 4*qd);
            unsigned xh0,xh1,xl0,xl1;
            split4(v, xh0, xh1, xl0, xl1);
            bf8 Bh = mk_bhh(xh0, xh1);
            bf8 Bl = mk_bl0(xl0, xl1);
            #pragma unroll
            for (int Mi = 0; Mi < 4; ++Mi) {
                u4 w = wtp[(n*4+Mi)*64 + lane];
                tacc[Mi] = mfma2(tacc[Mi], afrag(w), Bh, Bl);
            }
        }
        #pragma unroll
        for (int Mi = 0; Mi < 4; ++Mi)
            tacc[Mi] += *(const f4*)(cproj + (size_t)(b*NVAR+n)*DD + 16*Mi + 4*qd);
        acc_to_frags1(tacc, fh, fl);   // a-frags

        // res = Wp^T @ a + rbias  (== Wp^T t + bp; rbias precomputed fp32)
        f4 racc[4];
        #pragma unroll
        for (int Mi = 0; Mi < 4; ++Mi)
            racc[Mi] = *(const f4*)(rbias + (size_t)(b*NVAR+n)*DD + 16*Mi + 4*qd);
        run_stage2(bigp + (n*4 + 0)*1024, lane, fh, fl, racc);

        // h1 = elu(W1^T @ a + b1)
        f4 hacc[4];
        #pragma unroll
        for (int Mi = 0; Mi < 4; ++Mi) hacc[Mi] = *(const f4*)(b1 + n*DD + 16*Mi + 4*qd);
        run_stage2(bigp + (n*4 + 1)*1024, lane, fh, fl, hacc);
        #pragma unroll
        for (int Mi = 0; Mi < 4; ++Mi) {
            f4& v = hacc[Mi];
            v.x = v.x > 0.f ? v.x : (__expf(v.x)-1.f);
            v.y = v.y > 0.f ? v.y : (__expf(v.y)-1.f);
            v.z = v.z > 0.f ? v.z : (__expf(v.z)-1.f);
            v.w = v.w > 0.f ? v.w : (__expf(v.w)-1.f);
        }
        acc_to_frags1(hacc, fh, fl);   // h1 frags

        // h2 = W2^T @ h1 + b2
        #pragma unroll
        for (int Mi = 0; Mi < 4; ++Mi) hacc[Mi] = *(const f4*)(b2 + n*DD + 16*Mi + 4*qd);
        run_stage2(bigp + (n*4 + 2)*1024, lane, fh, fl, hacc);
        acc_to_frags1(hacc, fh, fl);   // h2 frags (fp32 recon from hi+lo below)

        // gate logits = Wg^T @ h2 + bg
        f4 gacc[4];
        #pragma unroll
        for (int Mi = 0; Mi < 4; ++Mi) gacc[Mi] = *(const f4*)(bg + n*DD + 16*Mi + 4*qd);
        run_stage2(bigp + (n*4 + 3)*1024, lane, fh, fl, gacc);

        // z = sigmoid(g)*h2 + res
        f4 z[4];
        #pragma unroll
        for (int Mi = 0; Mi < 4; ++Mi) {
            float h2x = bflo(fh[Mi][0]) + bflo(fl[Mi][0]);
            float h2y = bfhi(fh[Mi][0]) + bfhi(fl[Mi][0]);
            float h2z = bflo(fh[Mi][1]) + bflo(fl[Mi][1]);
            float h2w = bfhi(fh[Mi][1]) + bfhi(fl[Mi][1]);
            f4 gv = gacc[Mi];
            z[Mi].x = h2x / (1.f+__expf(-gv.x)) + racc[Mi].x;
            z[Mi].y = h2y / (1.f+__expf(-gv.y)) + racc[Mi].y;
            z[Mi].z = h2z / (1.f+__expf(-gv.z)) + racc[Mi].z;
            z[Mi].w = h2w / (1.f+__expf(-gv.w)) + racc[Mi].w;
        }
        // LayerNorm over d (16 in-lane + cross-quad butterfly)
        float s = 0.f;
        #pragma unroll
        for (int Mi = 0; Mi < 4; ++Mi) s += z[Mi].x + z[Mi].y + z[Mi].z + z[Mi].w;
        s += __shfl_xor(s, 16);
        s += __shfl_xor(s, 32);
        float mu = s * (1.f/64.f);
        float q = 0.f;
        #pragma unroll
        for (int Mi = 0; Mi < 4; ++Mi) {
            float dx = z[Mi].x - mu; q += dx*dx;
            dx = z[Mi].y - mu; q += dx*dx;
            dx = z[Mi].z - mu; q += dx*dx;
            dx = z[Mi].w - mu; q += dx*dx;
        }
        q += __shfl_xor(q, 16);
        q += __shfl_xor(q, 32);
        float rstd = rsqrtf(q*(1.f/64.f) + LN_EPS);

        float wn = smem[WSEL_OFF + tq*272 + n*17 + l15];
        #pragma unroll
        for (int Mi = 0; Mi < 4; ++Mi) {
            f4 gm = *(const f4*)(gamma_ + n*DD + 16*Mi + 4*qd);
            f4 bb = *(const f4*)(beta_  + n*DD + 16*Mi + 4*qd);
            sel[Mi].x += wn*((z[Mi].x-mu)*rstd*gm.x + bb.x);
            sel[Mi].y += wn*((z[Mi].y-mu)*rstd*gm.y + bb.y);
            sel[Mi].z += wn*((z[Mi].z-mu)*rstd*gm.z + bb.z);
            sel[Mi].w += wn*((z[Mi].w-mu)*rstd*gm.w + bb.w);
        }
    }

    // partial sel -> LDS row (grp*64 + tq*16 + l15), stride 68 dw (17x16B, aligned)
    {
        int base = PSEL_OFF + (grp*64 + tq*16 + l15)*68;
        #pragma unroll
        for (int Mi = 0; Mi < 4; ++Mi)
            *(f4*)&smem[base + 16*Mi + 4*qd] = sel[Mi];
    }
    __syncthreads();
    {
        int tokloc = tid >> 3;            // 0..63 (the 64 tokens of this tile)
        int d0 = (tid & 7) * 8;
        int rbase = PSEL_OFF + tokloc*68 + d0;
        f4 a0 = *(f4*)&smem[rbase];
        f4 a1 = *(f4*)&smem[rbase + 4];
        f4 b0 = *(f4*)&smem[rbase + 64*68];
        f4 b1v = *(f4*)&smem[rbase + 64*68 + 4];
        float* po = out_sel + (size_t)(tile0+tokloc)*DD + d0;
        *(f4*)po     = a0 + b0;
        *(f4*)(po+4) = a1 + b1v;
    }
}

extern "C" void kernel_launch(void* const* d_in, const int* in_sizes, int n_in,
                              void* d_out, int out_size, void* d_ws, size_t ws_size,
                              hipStream_t stream) {
    const float* inp  = (const float*)d_in[0];
    const float* ctx  = (const float*)d_in[1];
    const float* Wt   = (const float*)d_in[2];
    const float* bt   = (const float*)d_in[3];
    const float* Wctx = (const float*)d_in[4];
    const float* W1   = (const float*)d_in[5];
    const float* b1   = (const float*)d_in[6];
    const float* W2   = (const float*)d_in[7];
    const float* b2   = (const float*)d_in[8];
    const float* Wg   = (const float*)d_in[9];
    const float* bg   = (const float*)d_in[10];
    const float* Wp   = (const float*)d_in[11];
    const float* bp   = (const float*)d_in[12];
    const float* gm   = (const float*)d_in[13];
    const float* bt2  = (const float*)d_in[14];
    const float* Ws   = (const float*)d_in[15];
    const float* bs   = (const float*)d_in[16];

    float* out_sel = (float*)d_out;
    float* out_w   = out_sel + (size_t)BT * DD;

    char* ws = (char*)d_ws;
    float* cproj = (float*)(ws + CPROJ_OFF);
    float* rbias = (float*)(ws + RBIAS_OFF);
    u4* wtp  = (u4*)(ws + WTP_OFF);
    u4* bigp = (u4*)(ws + BIGP_OFF);
    u4* wsp  = (u4*)(ws + WSP_OFF);

    prep_kernel<<<532, 256, 0, stream>>>(Wt, W1, W2, Wg, Wp, Ws, ctx, Wctx,
                                         wtp, bigp, wsp, cproj);
    rbias_kernel<<<NB * NVAR, DD, 0, stream>>>(cproj, Wp, bp, rbias);
    vsn_kernel<<<BT / 64, 512, 0, stream>>>(inp, wtp, bigp, wsp,
                                            bt, b1, b2, bg, rbias, gm, bt2, bs,
                                            cproj, out_sel, out_w);
}